// Round 3
// baseline (713.945 us; speedup 1.0000x reference)
//
#include <hip/hip_runtime.h>
#include <stdint.h>

// Problem constants
#define MROWS 32768      // B*S = 8*4096
#define KD    256        // 2*DIM
#define VOCABN 8192

typedef _Float16 half8  __attribute__((ext_vector_type(8)));
typedef _Float16 half4v __attribute__((ext_vector_type(4)));
typedef float  floatx4  __attribute__((ext_vector_type(4)));

// scratch layout (byte offsets within d_ws; ws_size >= WS_NEED verified R3/R4)
#define A_OFF     0u          // f16 z  [32768][256]  = 16,777,216 B
#define B_OFF     16777216u   // f16 cb [8192][256]   =  4,194,304 B
#define CN_OFF    20971520u   // f32 0.5*||c||^2 [8192] = 32,768 B
#define PART_OFF  21004288u   // float4 top2 [32768][8] = 4,194,304 B
#define IDX_OFF   25198592u   // int idx [32768] = 131,072 B
#define WS_NEED   25329664u

// ---- top-2 (max sigma) with smaller-index tie-break (flush/merge path) ----
struct Top2 { float s1; int i1; float s2; int i2; };

__device__ __forceinline__ bool better(float sa, int ia, float sb, int ib) {
    return (sa > sb) || (sa == sb && ia < ib);
}
__device__ __forceinline__ Top2 merge2(const Top2& a, const Top2& b) {
    Top2 r;
    if (better(b.s1, b.i1, a.s1, a.i1)) {
        r.s1 = b.s1; r.i1 = b.i1;
        if (better(a.s1, a.i1, b.s2, b.i2)) { r.s2 = a.s1; r.i2 = a.i1; }
        else                                { r.s2 = b.s2; r.i2 = b.i2; }
    } else {
        r.s1 = a.s1; r.i1 = a.i1;
        if (better(b.s1, b.i1, a.s2, a.i2)) { r.s2 = b.s1; r.i2 = b.i1; }
        else                                { r.s2 = a.s2; r.i2 = a.i2; }
    }
    return r;
}

// async global->LDS, 16 B per lane. LDS dest is WAVE-UNIFORM base + lane*16;
// global src is per-lane (swizzle is applied by pre-permuting the src).
__device__ __forceinline__ void gll16(const void* g, const void* l) {
    __builtin_amdgcn_global_load_lds(
        (const __attribute__((address_space(1))) void*)g,
        (__attribute__((address_space(3))) void*)l, 16, 0, 0);
}

// counted-vmcnt pipe barrier (T3/T4): drain to N outstanding, raw s_barrier.
// NEVER vmcnt(0) in the main loop; sched_barrier(0) pins reordering.
#define PIPE_SYNC(N) do {                                        \
    asm volatile("s_waitcnt vmcnt(" #N ")" ::: "memory");        \
    __builtin_amdgcn_s_barrier();                                \
    __builtin_amdgcn_sched_barrier(0);                           \
} while (0)

// ---- 1. z = concat(real,imag) as f16 [32768][256] ----
__global__ __launch_bounds__(256) void prep_z(const float* __restrict__ gr,
                                              const float* __restrict__ gi,
                                              _Float16* __restrict__ A) {
    int t = blockIdx.x * 256 + threadIdx.x;     // 4 elements/thread
    int base = t * 4;
    int m = base >> 8;
    int k = base & 255;
    float4 v;
    if (k < 128) v = *(const float4*)(gr + (size_t)m * 128 + k);
    else         v = *(const float4*)(gi + (size_t)m * 128 + (k - 128));
    half4v h;
    h[0] = (_Float16)v.x; h[1] = (_Float16)v.y;
    h[2] = (_Float16)v.z; h[3] = (_Float16)v.w;
    *(half4v*)(A + base) = h;
}

// ---- 2. codebook f16 [8192][256] + 0.5*||c||^2 fp32 ----
__global__ __launch_bounds__(64) void prep_c(const float* __restrict__ cb,
                                             _Float16* __restrict__ B,
                                             float* __restrict__ cnorm) {
    int v = blockIdx.x;
    int lane = threadIdx.x;                    // 0..63, 4 floats each
    float4 c = ((const float4*)(cb + (size_t)v * 256))[lane];
    half4v h;
    h[0] = (_Float16)c.x; h[1] = (_Float16)c.y;
    h[2] = (_Float16)c.z; h[3] = (_Float16)c.w;
    ((half4v*)(B + (size_t)v * 256))[lane] = h;
    float s = c.x * c.x + c.y * c.y + c.z * c.z + c.w * c.w;
    #pragma unroll
    for (int m = 32; m; m >>= 1) s += __shfl_xor(s, m);
    if (lane == 0) cnorm[v] = 0.5f * s;
}

// ---- 3. f16 GEMM + per-row top-2 argmax(sigma) ----
// R16 post-mortem: counted-vmcnt pipeline worked (300us, conflicts=0) but
// MfmaUtil 19.8% x 300us = 59us matrix-pipe busy = the 16x16-shape floor --
// everything else is exposed latency at only 2 waves/SIMD (grid 512 = the
// occupancy cap, not LDS). R17: same 64x128 block, 512 THREADS (8 waves 2x4),
// slice = 8 KB (128 cols x 32 k), 4 buffers + cnorm + topbuf = 38 KB LDS,
// launch_bounds(512,4) -> 2 blocks/CU = 4 waves/SIMD (2x latency hiding)
// while B-through-L2 stays 512x4MB = 2 GB (58us floor; MFMA floor 66us).
// Depth-3 prefetch, 1 stage-load/wave/slice -> PIPE_SYNC(2). Swizzle: LDS
// [col][64B] rows; phys chunk = logical ^ (col&3) ^ ((col>>2)&3) -> 8-way
// spread of b128 chunk-columns (the 2-way floor, free per m136).
__global__ __launch_bounds__(512, 4) void gemm_argmin(
        const _Float16* __restrict__ A, const _Float16* __restrict__ B,
        const float* __restrict__ cnorm, float4* __restrict__ part) {
    // LDS: 4 x 8 KB buffers | 2 x 1 KB cnorm | 4 KB topbuf = 38 KB
    __shared__ __align__(16) char lds[38912];
    float4* topbuf = (float4*)(lds + 34816);

    const int tid = threadIdx.x;
    const int m0 = blockIdx.x * 64;
    const int wave = tid >> 6, lane = tid & 63;
    const int wr = wave >> 2, wc = wave & 3;   // 2x4: 32 rows x 32 cols/wave
    const int lane16 = lane & 15, quad = lane >> 4;

    // A-fragments from global once: row m0+wr*32+i*16+lane16, k=h*32+quad*8
    half8 af[2][8];
    #pragma unroll
    for (int i = 0; i < 2; ++i) {
        const _Float16* ar = A + (size_t)(m0 + wr * 32 + i * 16 + lane16) * 256
                               + quad * 8;
        #pragma unroll
        for (int h = 0; h < 8; ++h)
            af[i][h] = *(const half8*)(ar + h * 32);
    }

    // staging: wave stages local cols [wave*16,+16) = 1 KB = 1 gll16/slice.
    // lane L -> col = wave*16 + (L>>2), phys chunk L&3, fetch logical chunk
    // (L&3)^((L>>2)&3)^((L>>4)&3)  [= pc ^ f(col), f(c)=(c&3)^((c>>2)&3)]
    const int l2 = lane >> 2;
    const int lcs = (lane & 3) ^ (l2 & 3) ^ ((lane >> 4) & 3);
    const _Float16* gb = B + (size_t)(wave * 16 + l2) * 256 + lcs * 8;
    const uint32_t lw = (uint32_t)wave * 1024;

    // fragment ds_read: col = wc*32+j*16+lane16, byte = col*64 + phys*16,
    // phys = quad ^ (lane16&3) ^ ((lane16>>2)&3)
    const uint32_t cq = (uint32_t)((quad ^ (lane16 & 3) ^ ((lane16 >> 2) & 3)) * 16);
    const uint32_t frb = (uint32_t)(wc * 32 + lane16) * 64 + cq;

    Top2 t2[2][4];
    #pragma unroll
    for (int i = 0; i < 2; ++i)
        #pragma unroll
        for (int r = 0; r < 4; ++r)
            t2[i][r] = Top2{-3.4e38f, 0x7fffffff, -3.4e38f, 0x7fffffff};

    // stage slice v (buffer v&3). do_cn (h==5 call sites, v%8==0): wave0 also
    // stages cnorm[g*128..+128) (dup'd x2 via lane&31) into slot (g&1).
    auto STAGE = [&](int v, bool do_cn) {
        const size_t off = ((size_t)(v >> 3) << 15) + (size_t)((v & 7) * 32);
        gll16(gb + off, lds + (v & 3) * 8192 + lw);
        if (do_cn && wave == 0)
            gll16(cnorm + (v >> 3) * 128 + (lane & 31) * 4,
                  lds + 32768 + ((v >> 3) & 1) * 1024);
    };

    // compute slice with k-chunk h (buffer h&3): 2 ds_read_b128 + 4 MFMA
    auto COMPUTE = [&](int h, floatx4 (&acc)[2][2]) {
        const char* cur = lds + (h & 3) * 8192;
        half8 bf[2];
        #pragma unroll
        for (int j = 0; j < 2; ++j)
            bf[j] = *(const half8*)(cur + frb + j * 1024);
        #pragma unroll
        for (int i = 0; i < 2; ++i)
            #pragma unroll
            for (int j = 0; j < 2; ++j)
                acc[i][j] = __builtin_amdgcn_mfma_f32_16x16x32_f16(
                    af[i][h], bf[j], acc[i][j], 0, 0, 0);
    };

    auto ACCINIT = [&](int g, floatx4 (&acc)[2][2]) {
        const float* cl = (const float*)(lds + 32768 + (g & 1) * 1024)
                          + wc * 32 + lane16;
        #pragma unroll
        for (int j = 0; j < 2; ++j) {
            float nh = -cl[j * 16];
            acc[0][j] = (floatx4){nh, nh, nh, nh};
            acc[1][j] = acc[0][j];
        }
    };

    // streaming top-2 (C/D layout: col=lane&15, row=quad*4+r). Cheap form;
    // exact ties deferred to resolve's fp64 refine.
    auto TOP2 = [&](int g, floatx4 (&acc)[2][2]) {
        const int colb = g * 128 + wc * 32 + lane16;
        #pragma unroll
        for (int i = 0; i < 2; ++i)
            #pragma unroll
            for (int r = 0; r < 4; ++r) {
                Top2& t = t2[i][r];
                #pragma unroll
                for (int j = 0; j < 2; ++j) {
                    float sv = acc[i][j][r];
                    int col = colb + j * 16;
                    bool gt1 = sv > t.s1;
                    bool gt2 = sv > t.s2;
#if __has_builtin(__builtin_amdgcn_fmed3f)
                    float ns2 = __builtin_amdgcn_fmed3f(sv, t.s2, t.s1);
#else
                    float ns2 = gt1 ? t.s1 : (gt2 ? sv : t.s2);
#endif
                    t.i2 = gt1 ? t.i1 : (gt2 ? col : t.i2);
                    t.i1 = gt1 ? col : t.i1;
                    t.s1 = gt1 ? sv  : t.s1;
                    t.s2 = ns2;
                }
            }
    };

    // flush: 16-lane butterfly + cross-wave merge via topbuf[64][4] + part
    // write. lgkm-only barriers -- staged loads stay in flight.
    auto FLUSH = [&](int slot) {
        #pragma unroll
        for (int i = 0; i < 2; ++i)
            #pragma unroll
            for (int r = 0; r < 4; ++r) {
                Top2 t = t2[i][r];
                #pragma unroll
                for (int m = 1; m < 16; m <<= 1) {
                    Top2 o;
                    o.s1 = __shfl_xor(t.s1, m); o.i1 = __shfl_xor(t.i1, m);
                    o.s2 = __shfl_xor(t.s2, m); o.i2 = __shfl_xor(t.i2, m);
                    t = merge2(t, o);
                }
                if (lane16 == 0) {
                    int rl = wr * 32 + i * 16 + quad * 4 + r;   // 0..63
                    topbuf[rl * 4 + wc] =
                        make_float4(t.s1, __int_as_float(t.i1),
                                    t.s2, __int_as_float(t.i2));
                }
                t2[i][r] = Top2{-3.4e38f, 0x7fffffff, -3.4e38f, 0x7fffffff};
            }
        asm volatile("s_waitcnt lgkmcnt(0)" ::: "memory");
        __builtin_amdgcn_s_barrier();
        __builtin_amdgcn_sched_barrier(0);
        if (tid < 64) {
            float4 e0 = topbuf[tid * 4 + 0], e1 = topbuf[tid * 4 + 1];
            float4 e2 = topbuf[tid * 4 + 2], e3 = topbuf[tid * 4 + 3];
            Top2 a{e0.x, __float_as_int(e0.y), e0.z, __float_as_int(e0.w)};
            Top2 b{e1.x, __float_as_int(e1.y), e1.z, __float_as_int(e1.w)};
            Top2 c{e2.x, __float_as_int(e2.y), e2.z, __float_as_int(e2.w)};
            Top2 d{e3.x, __float_as_int(e3.y), e3.z, __float_as_int(e3.w)};
            Top2 t = merge2(merge2(merge2(a, b), c), d);
            part[(size_t)(m0 + tid) * 8 + slot] =
                make_float4(t.s1, __int_as_float(t.i1),
                            t.s2, __int_as_float(t.i2));
        }
        asm volatile("s_waitcnt lgkmcnt(0)" ::: "memory");
        __builtin_amdgcn_s_barrier();
        __builtin_amdgcn_sched_barrier(0);
    };

    // prologue: fill 3 stages; drain batch 0 (incl cnorm g0 on wave0)
    STAGE(0, true); STAGE(1, false); STAGE(2, false);
    PIPE_SYNC(2);

    for (int g = 0; g < 63; ++g) {
        floatx4 acc[2][2];
        ACCINIT(g, acc);
        const int v0 = g * 8;
        #pragma unroll
        for (int h = 0; h < 8; ++h) {
            STAGE(v0 + h + 3, h == 5);   // h==5 -> v%8==0 -> cnorm for g+1
            COMPUTE(h, acc);
            PIPE_SYNC(2);                // drains exactly batch v+1
        }
        TOP2(g, acc);
        if ((g & 7) == 7) FLUSH(g >> 3);
    }
    {   // g = 63 peeled: drain with descending counted waits
        floatx4 acc[2][2];
        ACCINIT(63, acc);
        #pragma unroll
        for (int h = 0; h < 5; ++h) {
            STAGE(507 + h, false);
            COMPUTE(h, acc);
            PIPE_SYNC(2);
        }
        COMPUTE(5, acc); PIPE_SYNC(1);
        COMPUTE(6, acc); PIPE_SYNC(0);
        COMPUTE(7, acc);
        TOP2(63, acc);
        FLUSH(7);
    }
}

// ---- 4. resolve: merge 8 partials/row + WAVE-COOPERATIVE fp64 refine ----
// R17: old per-thread serial refine (16 cands x 128-iter fp64 under exec-mask
// divergence) made every wave pay the union -- suspected bulk of the ~227us
// non-gemm time. Now: compact (row,cand) pairs to LDS, one wave per candidate
// (64 lanes x 4 dims, fp64 shuffle-reduce), then each row scans its results.
// zero_vq folded in (block 0 thread 0).
__global__ __launch_bounds__(256) void resolve(const float4* __restrict__ part,
                                               const float* __restrict__ gr,
                                               const float* __restrict__ gi,
                                               const float* __restrict__ cb,
                                               int* __restrict__ idx,
                                               float* __restrict__ out,
                                               size_t vq_off) {
    __shared__ int s_cnt;
    __shared__ int2 ent[2048];
    __shared__ double res[2048];

    const int tid = threadIdx.x;
    const int row = blockIdx.x * 256 + tid;   // grid 128
    if (blockIdx.x == 0 && tid == 0) out[vq_off] = 0.f;
    if (tid == 0) s_cnt = 0;

    float4 e[8];
    #pragma unroll
    for (int j = 0; j < 8; ++j) e[j] = part[(size_t)row * 8 + j];
    Top2 t{-3.4e38f, 0x7fffffff, -3.4e38f, 0x7fffffff};
    #pragma unroll
    for (int j = 0; j < 8; ++j) {
        Top2 o{e[j].x, __float_as_int(e[j].y), e[j].z, __float_as_int(e[j].w)};
        t = merge2(t, o);
    }
    int best = t.i1;
    const float MARGIN = 0.12f;   // ~7.7 sigma of f16-screen score-diff noise
    const float cut = t.s1 - MARGIN;
    const bool need = (t.s1 - t.s2 < MARGIN);
    __syncthreads();              // s_cnt initialized

    int nc = 0;
    if (need) {
        #pragma unroll
        for (int j = 0; j < 8; ++j)
            #pragma unroll
            for (int c = 0; c < 2; ++c) {
                float sv = c ? e[j].z : e[j].x;
                int   ci = __float_as_int(c ? e[j].w : e[j].y);
                nc += (sv >= cut && (unsigned)ci < 8192u) ? 1 : 0;
            }
    }
    int mybase = 0;
    bool serial = false;
    if (nc) {
        mybase = atomicAdd(&s_cnt, nc);
        if (mybase + nc <= 2048) {
            int k = 0;
            #pragma unroll
            for (int j = 0; j < 8; ++j)
                #pragma unroll
                for (int c = 0; c < 2; ++c) {
                    float sv = c ? e[j].z : e[j].x;
                    int   ci = __float_as_int(c ? e[j].w : e[j].y);
                    if (sv >= cut && (unsigned)ci < 8192u)
                        ent[mybase + (k++)] = make_int2(row, ci);
                }
        } else serial = true;     // overflow fallback (needs >8 cands/row avg)
    }
    __syncthreads();
    const int cnt = (s_cnt < 2048) ? s_cnt : 2048;
    const int wave = tid >> 6, lane = tid & 63;
    for (int ee = wave; ee < cnt; ee += 4) {
        int2 rc = ent[ee];
        float4 c4 = ((const float4*)(cb + (size_t)rc.y * 256))[lane];
        float4 z4 = (lane < 32)
                  ? ((const float4*)(gr + (size_t)rc.x * 128))[lane]
                  : ((const float4*)(gi + (size_t)rc.x * 128))[lane - 32];
        double dx = (double)z4.x - (double)c4.x;
        double dy = (double)z4.y - (double)c4.y;
        double dz = (double)z4.z - (double)c4.z;
        double dw = (double)z4.w - (double)c4.w;
        double d = dx * dx + dy * dy + dz * dz + dw * dw;
        #pragma unroll
        for (int m = 1; m < 64; m <<= 1) d += __shfl_xor(d, m);
        if (lane == 0) res[ee] = d;
    }
    __syncthreads();
    if (nc && !serial) {
        double bd = 1e300; int bi = 0x7fffffff;
        for (int k = 0; k < nc; ++k) {
            double d = res[mybase + k];
            int   ci = ent[mybase + k].y;
            if (d < bd || (d == bd && ci < bi)) { bd = d; bi = ci; }
        }
        if ((unsigned)bi < 8192u) best = bi;
    } else if (serial) {          // old proven serial path (rare)
        double bd = 1e300; int bi = 0x7fffffff;
        const float* zr = gr + (size_t)row * 128;
        const float* zi = gi + (size_t)row * 128;
        #pragma unroll
        for (int j = 0; j < 8; ++j)
            #pragma unroll
            for (int c = 0; c < 2; ++c) {
                float sv = c ? e[j].z : e[j].x;
                int   ci = __float_as_int(c ? e[j].w : e[j].y);
                if (sv >= cut && (unsigned)ci < 8192u) {
                    const float* crow = cb + (size_t)ci * 256;
                    double d = 0.0;
                    for (int k = 0; k < 128; ++k) {
                        double a = (double)zr[k] - (double)crow[k];
                        double b = (double)zi[k] - (double)crow[128 + k];
                        d += a * a + b * b;
                    }
                    if (d < bd || (d == bd && ci < bi)) { bd = d; bi = ci; }
                }
            }
        if ((unsigned)bi < 8192u) best = bi;
    }
    idx[row] = ((unsigned)best < 8192u) ? best : 0;
}

// ---- 5. gather + proposal(REAL part only) + salience + vq (one wave/row) ----
__global__ __launch_bounds__(256) void gather_epi(const int* __restrict__ idx,
                                                  const float* __restrict__ gr,
                                                  const float* __restrict__ gi,
                                                  const float* __restrict__ cb,
                                                  const float* __restrict__ salw,
                                                  const float* __restrict__ salb,
                                                  float* __restrict__ out,
                                                  size_t sal_off, size_t vq_off) {
    const int wave = threadIdx.x >> 6, lane = threadIdx.x & 63;
    const int row = blockIdx.x * 4 + wave;
    int id = idx[row];
    if ((unsigned)id >= 8192u) id = 0;   // clamp: no wild reads

    float4 c4 = ((const float4*)(cb + (size_t)id * 256))[lane];
    float4 z4 = (lane < 32) ? ((const float4*)(gr + (size_t)row * 128))[lane]
                            : ((const float4*)(gi + (size_t)row * 128))[lane - 32];

    float dx = c4.x - z4.x, dy = c4.y - z4.y, dz = c4.z - z4.z, dw = c4.w - z4.w;
    float vq = dx * dx + dy * dy + dz * dz + dw * dw;
    float4 w4 = ((const float4*)salw)[lane];
    float sal = c4.x * w4.x + c4.y * w4.y + c4.z * w4.z + c4.w * w4.w;
    #pragma unroll
    for (int m = 1; m < 64; m <<= 1) {
        vq  += __shfl_xor(vq, m);
        sal += __shfl_xor(sal, m);
    }

    // proposal: real part only — lanes 0..31 hold c[0..128) as float4s
    if (lane < 32 && (size_t)(row + 1) * 128 <= sal_off) {
        float4* op = (float4*)(out + (size_t)row * 128);
        op[lane] = c4;
    }
    if (lane == 0 && sal_off + row < vq_off)
        out[sal_off + row] = sal + salb[0];

    __shared__ float vqs[4];
    if (lane == 0) vqs[wave] = vq;
    __syncthreads();
    if (threadIdx.x == 0) {
        float p = (vqs[0] + vqs[1] + vqs[2] + vqs[3]) * (1.25f / 8388608.f);
        atomicAdd(out + vq_off, p);
    }
}

extern "C" void kernel_launch(void* const* d_in, const int* in_sizes, int n_in,
                              void* d_out, int out_size, void* d_ws, size_t ws_size,
                              hipStream_t stream) {
    const float* gr = (const float*)d_in[0];   // gw_real  [8,4096,128]
    const float* gi = (const float*)d_in[1];   // gw_imag  [8,4096,128]
    const float* cb = (const float*)d_in[2];   // codebook [8192,256]
    const float* sw = (const float*)d_in[3];   // sal_w    [1,256]
    const float* sb = (const float*)d_in[4];   // sal_b    [1]
    float* out = (float*)d_out;

    // Output offsets (out_size = 4,227,073 floats:
    // proposal-real 4,194,304 | salience 32,768 | vq_loss 1).
    size_t vq_off  = (size_t)out_size - 1;
    size_t sal_off = (size_t)out_size - 1 - 32768;

    char* base = (char*)d_ws;
    int*  idxb = (int*)(base + IDX_OFF);
    _Float16* A    = (_Float16*)(base + A_OFF);
    _Float16* Bq   = (_Float16*)(base + B_OFF);
    float*    cn   = (float*)   (base + CN_OFF);
    float4*   part = (float4*)  (base + PART_OFF);

    prep_z<<<8192, 256, 0, stream>>>(gr, gi, A);
    prep_c<<<8192, 64, 0, stream>>>(cb, Bq, cn);
    gemm_argmin<<<512, 512, 0, stream>>>(A, Bq, cn, part);
    resolve<<<128, 256, 0, stream>>>(part, gr, gi, cb, idxb, out, vq_off);
    gather_epi<<<8192, 256, 0, stream>>>(idxb, gr, gi, cb, sw, sb, out,
                                         sal_off, vq_off);
}

// Round 4
// 477.140 us; speedup vs baseline: 1.4963x; 1.4963x over previous
//
#include <hip/hip_runtime.h>
#include <stdint.h>

// Problem constants
#define MROWS 32768      // B*S = 8*4096
#define KD    256        // 2*DIM
#define VOCABN 8192

typedef _Float16 half8  __attribute__((ext_vector_type(8)));
typedef _Float16 half4v __attribute__((ext_vector_type(4)));
typedef float  floatx4  __attribute__((ext_vector_type(4)));

// scratch layout (byte offsets within d_ws; ws_size >= WS_NEED verified R3/R4)
#define A_OFF     0u          // f16 z  [32768][256]  = 16,777,216 B
#define B_OFF     16777216u   // f16 cb [8192][256]   =  4,194,304 B
#define CN_OFF    20971520u   // f32 0.5*||c||^2 [8192] = 32,768 B
#define PART_OFF  21004288u   // float4 top2 [32768][8] = 4,194,304 B
#define IDX_OFF   25198592u   // int idx [32768] = 131,072 B
#define WS_NEED   25329664u

// ---- top-2 (max sigma) with smaller-index tie-break (flush/merge path) ----
struct Top2 { float s1; int i1; float s2; int i2; };

__device__ __forceinline__ bool better(float sa, int ia, float sb, int ib) {
    return (sa > sb) || (sa == sb && ia < ib);
}
__device__ __forceinline__ Top2 merge2(const Top2& a, const Top2& b) {
    Top2 r;
    if (better(b.s1, b.i1, a.s1, a.i1)) {
        r.s1 = b.s1; r.i1 = b.i1;
        if (better(a.s1, a.i1, b.s2, b.i2)) { r.s2 = a.s1; r.i2 = a.i1; }
        else                                { r.s2 = b.s2; r.i2 = b.i2; }
    } else {
        r.s1 = a.s1; r.i1 = a.i1;
        if (better(b.s1, b.i1, a.s2, a.i2)) { r.s2 = b.s1; r.i2 = b.i1; }
        else                                { r.s2 = a.s2; r.i2 = a.i2; }
    }
    return r;
}

// async global->LDS, 16 B per lane. LDS dest is WAVE-UNIFORM base + lane*16;
// global src is per-lane (swizzle is applied by pre-permuting the src).
__device__ __forceinline__ void gll16(const void* g, const void* l) {
    __builtin_amdgcn_global_load_lds(
        (const __attribute__((address_space(1))) void*)g,
        (__attribute__((address_space(3))) void*)l, 16, 0, 0);
}

// counted-vmcnt pipe barrier (T3/T4): drain to N outstanding, raw s_barrier.
// NEVER vmcnt(0) in the main loop; sched_barrier(0) pins reordering.
#define PIPE_SYNC(N) do {                                        \
    asm volatile("s_waitcnt vmcnt(" #N ")" ::: "memory");        \
    __builtin_amdgcn_s_barrier();                                \
    __builtin_amdgcn_sched_barrier(0);                           \
} while (0)

// ---- 1. z = concat(real,imag) as f16 [32768][256] ----
__global__ __launch_bounds__(256) void prep_z(const float* __restrict__ gr,
                                              const float* __restrict__ gi,
                                              _Float16* __restrict__ A) {
    int t = blockIdx.x * 256 + threadIdx.x;     // 4 elements/thread
    int base = t * 4;
    int m = base >> 8;
    int k = base & 255;
    float4 v;
    if (k < 128) v = *(const float4*)(gr + (size_t)m * 128 + k);
    else         v = *(const float4*)(gi + (size_t)m * 128 + (k - 128));
    half4v h;
    h[0] = (_Float16)v.x; h[1] = (_Float16)v.y;
    h[2] = (_Float16)v.z; h[3] = (_Float16)v.w;
    *(half4v*)(A + base) = h;
}

// ---- 2. codebook f16 [8192][256] + 0.5*||c||^2 fp32 ----
__global__ __launch_bounds__(64) void prep_c(const float* __restrict__ cb,
                                             _Float16* __restrict__ B,
                                             float* __restrict__ cnorm) {
    int v = blockIdx.x;
    int lane = threadIdx.x;                    // 0..63, 4 floats each
    float4 c = ((const float4*)(cb + (size_t)v * 256))[lane];
    half4v h;
    h[0] = (_Float16)c.x; h[1] = (_Float16)c.y;
    h[2] = (_Float16)c.z; h[3] = (_Float16)c.w;
    ((half4v*)(B + (size_t)v * 256))[lane] = h;
    float s = c.x * c.x + c.y * c.y + c.z * c.z + c.w * c.w;
    #pragma unroll
    for (int m = 32; m; m >>= 1) s += __shfl_xor(s, m);
    if (lane == 0) cnorm[v] = 0.5f * s;
}

// ---- 3. f16 GEMM + per-row top-2 argmax(sigma) ----
// R18 post-mortem (R17 = 512-thr rewrite): launch_bounds(512,4) let regalloc
// squeeze to 64 VGPR (demand ~140) -> af/t2 spilled to scratch (FETCH 26->423
// MB, WRITE 12->149 MB); and 64-B LDS rows are a STRUCTURAL 8-way bank
// conflict (bank = 16*(col&1)+4*chunk -> 8 banks; 1.7e7 conflicts). R19:
// revert to the R16-proven datapath byte-for-byte (112 VGPR, 128-B rows,
// zero conflicts, counted-vmcnt) and buy occupancy via LDS instead:
// 3 x 16-KB buffers (depth-2 prefetch) + cn 2 KB + topbuf 2 KB = 52 KB
// -> 3 blocks/CU (156 <= 160 KB) = 12 waves/CU = 3 waves/SIMD, 1.5x the
// latency hiding of R16's 2 blocks. mod-3 buffer index made compile-time
// by unrolling g in triples (63 = 21x3; g=63 peeled, drains 4/4/0).
// Floors: MFMA 66 us (16x16 rate), LDS B-read 55 us, L2 staging 62 us.
__global__ __launch_bounds__(256) void gemm_argmin(const _Float16* __restrict__ A,
                                                   const _Float16* __restrict__ B,
                                                   const float* __restrict__ cnorm,
                                                   float4* __restrict__ part) {
    // LDS: 3 x 16 KB slice buffers | 2 x 1 KB cnorm | 2 KB topbuf = 52 KB
    __shared__ __align__(16) char lds[53248];
    float4* topbuf = (float4*)(lds + 51200);

    const int tid = threadIdx.x;
    const int m0 = blockIdx.x * 64;
    const int wave = tid >> 6, lane = tid & 63;
    const int wr = wave >> 1, wc = wave & 1;           // 2x2: 32 rows x 64 cols
    const int lane16 = lane & 15, quad = lane >> 4;

    // A-fragments direct from global (once): row m0+wr*32+i*16+lane16,
    // k = s*64 + ks*32 + quad*8  (register-resident for the whole kernel)
    half8 af[2][4][2];   // [i][s(=h)][ks]
    #pragma unroll
    for (int i = 0; i < 2; ++i) {
        const _Float16* ar = A + (size_t)(m0 + wr * 32 + i * 16 + lane16) * 256
                               + quad * 8;
        #pragma unroll
        for (int s = 0; s < 4; ++s)
            #pragma unroll
            for (int ks = 0; ks < 2; ++ks)
                af[i][s][ks] = *(const half8*)(ar + s * 64 + ks * 32);
    }

    // ---- staging geometry (16-KB slice = [128 cols][128 B of k]) ----
    // Wave w stages cols [w*32,w*32+32) as 4 wave-loads of 1 KB (8 cols each).
    // Lane L -> col = colb + (L>>3), phys chunk L&7; fetches LOGICAL chunk
    // (L&7)^(L>>3) (col&7 == L>>3 here), so the XOR'd reader sees B[col][k].
    const int l3 = lane >> 3, l7 = lane & 7;
    const _Float16* pbase = B + (size_t)(wave * 32 + l3) * 256 + (l7 ^ l3) * 8;
    const uint32_t lwave = (uint32_t)wave * 4096;      // byte base in buffer

    // fragment ds_read offsets (bytes within a 16-KB buffer):
    // off(j,ks) = (wc*64+j*16+lane16)*128 + ((ks*4+quad) ^ (lane16&7))*16
    const uint32_t fr_base = (uint32_t)(wc * 64 + lane16) * 128;
    uint32_t cq[2];
    #pragma unroll
    for (int ks = 0; ks < 2; ++ks)
        cq[ks] = (uint32_t)(((ks * 4 + quad) ^ (lane16 & 7)) * 16);

    Top2 t2[2][4];
    #pragma unroll
    for (int i = 0; i < 2; ++i)
        #pragma unroll
        for (int r = 0; r < 4; ++r)
            t2[i][r] = Top2{-3.4e38f, 0x7fffffff, -3.4e38f, 0x7fffffff};

    // stage slice v into buffer b (b = v%3, compile-time at all call sites).
    // do_cn: wave0 also stages cnorm[g2*128..+128) into slot g2&1 (rides the
    // same vmcnt pipe; drained by the h=3 PIPE_SYNC before ACCINIT(g2)).
    auto STAGE = [&](int v, int b, bool do_cn) {
        const _Float16* src = pbase + ((size_t)(v >> 2) << 15)
                            + (size_t)((v & 3) * 64);
        char* dst = lds + b * 16384 + lwave;
        #pragma unroll
        for (int q = 0; q < 4; ++q)
            gll16(src + q * 2048, dst + q * 1024);
        if (do_cn && wave == 0) {
            int g2 = v >> 2;
            gll16(cnorm + g2 * 128 + (lane & 31) * 4,
                  lds + 49152 + (g2 & 1) * 1024);
        }
    };

    // compute k-chunk h of the current g from buffer b: 8 ds_read_b128 + 16 MFMA
    auto COMPUTE = [&](int b, int h, floatx4 (&acc)[2][4]) {
        const char* cur = lds + b * 16384;
        half8 bf[4][2];
        #pragma unroll
        for (int j = 0; j < 4; ++j)
            #pragma unroll
            for (int ks = 0; ks < 2; ++ks)
                bf[j][ks] = *(const half8*)(cur + fr_base + j * 2048 + cq[ks]);
        #pragma unroll
        for (int ks = 0; ks < 2; ++ks)
            #pragma unroll
            for (int i = 0; i < 2; ++i)
                #pragma unroll
                for (int j = 0; j < 4; ++j)
                    acc[i][j] = __builtin_amdgcn_mfma_f32_16x16x32_f16(
                        af[i][h][ks], bf[j][ks], acc[i][j], 0, 0, 0);
    };

    auto ACCINIT = [&](int g, floatx4 (&acc)[2][4]) {
        const float* cl = (const float*)(lds + 49152 + (g & 1) * 1024)
                          + wc * 64 + lane16;
        #pragma unroll
        for (int j = 0; j < 4; ++j) {
            float nh = -cl[j * 16];
            acc[0][j] = (floatx4){nh, nh, nh, nh};
            acc[1][j] = acc[0][j];
        }
    };

    // streaming top-2 (C/D layout: col=lane&15, row=quad*4+r). Cheap form;
    // exact ties deferred to resolve's fp64 refine.
    auto TOP2 = [&](int g, floatx4 (&acc)[2][4]) {
        const int colb = g * 128 + wc * 64 + lane16;
        #pragma unroll
        for (int i = 0; i < 2; ++i)
            #pragma unroll
            for (int r = 0; r < 4; ++r) {
                Top2& t = t2[i][r];
                #pragma unroll
                for (int j = 0; j < 4; ++j) {
                    float sv = acc[i][j][r];
                    int col = colb + j * 16;
                    bool gt1 = sv > t.s1;
                    bool gt2 = sv > t.s2;
#if __has_builtin(__builtin_amdgcn_fmed3f)
                    float ns2 = __builtin_amdgcn_fmed3f(sv, t.s2, t.s1);
#else
                    float ns2 = gt1 ? t.s1 : (gt2 ? sv : t.s2);
#endif
                    t.i2 = gt1 ? t.i1 : (gt2 ? col : t.i2);
                    t.i1 = gt1 ? col : t.i1;
                    t.s1 = gt1 ? sv  : t.s1;
                    t.s2 = ns2;
                }
            }
    };

    // flush: 16-lane butterfly + cross-wave merge via topbuf + part write.
    // lgkm-only barriers -- staged loads stay in flight.
    auto FLUSH = [&](int slot) {
        #pragma unroll
        for (int i = 0; i < 2; ++i)
            #pragma unroll
            for (int r = 0; r < 4; ++r) {
                Top2 t = t2[i][r];
                #pragma unroll
                for (int m = 1; m < 16; m <<= 1) {
                    Top2 o;
                    o.s1 = __shfl_xor(t.s1, m); o.i1 = __shfl_xor(t.i1, m);
                    o.s2 = __shfl_xor(t.s2, m); o.i2 = __shfl_xor(t.i2, m);
                    t = merge2(t, o);
                }
                if (lane16 == 0) {
                    int rl = wr * 32 + i * 16 + quad * 4 + r;   // 0..63
                    topbuf[rl * 2 + wc] =
                        make_float4(t.s1, __int_as_float(t.i1),
                                    t.s2, __int_as_float(t.i2));
                }
                t2[i][r] = Top2{-3.4e38f, 0x7fffffff, -3.4e38f, 0x7fffffff};
            }
        asm volatile("s_waitcnt lgkmcnt(0)" ::: "memory");
        __builtin_amdgcn_s_barrier();
        __builtin_amdgcn_sched_barrier(0);
        if (tid < 64) {
            float4 e0 = topbuf[tid * 2 + 0], e1 = topbuf[tid * 2 + 1];
            Top2 a{e0.x, __float_as_int(e0.y), e0.z, __float_as_int(e0.w)};
            Top2 b{e1.x, __float_as_int(e1.y), e1.z, __float_as_int(e1.w)};
            Top2 t = merge2(a, b);
            part[(size_t)(m0 + tid) * 8 + slot] =
                make_float4(t.s1, __int_as_float(t.i1),
                            t.s2, __int_as_float(t.i2));
        }
        asm volatile("s_waitcnt lgkmcnt(0)" ::: "memory");
        __builtin_amdgcn_s_barrier();
        __builtin_amdgcn_sched_barrier(0);
    };

    // prologue: fill 2 pipeline stages; sync(4) drains af loads + slice 0 + cn
    STAGE(0, 0, true); STAGE(1, 1, false);
    PIPE_SYNC(4);

    // main loop: g in triples so buf = (g*4+h)%3 = (gs+h)%3 is compile-time.
    // Per h: stage v+2 (depth-2), compute v, sync(4) (drains exactly v+1).
    for (int gg = 0; gg < 63; gg += 3) {
        #pragma unroll
        for (int gs = 0; gs < 3; ++gs) {
            const int g = gg + gs;
            floatx4 acc[2][4];
            ACCINIT(g, acc);
            #pragma unroll
            for (int h = 0; h < 4; ++h) {
                STAGE(g * 4 + h + 2, (gs + h + 2) % 3, h == 2);
                COMPUTE((gs + h) % 3, h, acc);
                PIPE_SYNC(4);
            }
            TOP2(g, acc);
            if ((g & 7) == 7) FLUSH(g >> 3);
        }
    }
    {   // g = 63 peeled (slices 252..255 -> bufs 0,1,2,0), descending drains
        floatx4 acc[2][4];
        ACCINIT(63, acc);
        STAGE(254, 2, false); COMPUTE(0, 0, acc); PIPE_SYNC(4);
        STAGE(255, 0, false); COMPUTE(1, 1, acc); PIPE_SYNC(4);
        COMPUTE(2, 2, acc);   PIPE_SYNC(0);
        COMPUTE(0, 3, acc);
        TOP2(63, acc);
        FLUSH(7);
    }
}

// ---- 4. resolve: merge 8 partials/row + WAVE-COOPERATIVE fp64 refine ----
// Compact (row,cand) pairs to LDS, one wave per candidate (64 lanes x 4 dims,
// fp64 shuffle-reduce), then each row scans its results. zero_vq folded in.
__global__ __launch_bounds__(256) void resolve(const float4* __restrict__ part,
                                               const float* __restrict__ gr,
                                               const float* __restrict__ gi,
                                               const float* __restrict__ cb,
                                               int* __restrict__ idx,
                                               float* __restrict__ out,
                                               size_t vq_off) {
    __shared__ int s_cnt;
    __shared__ int2 ent[2048];
    __shared__ double res[2048];

    const int tid = threadIdx.x;
    const int row = blockIdx.x * 256 + tid;   // grid 128
    if (blockIdx.x == 0 && tid == 0) out[vq_off] = 0.f;
    if (tid == 0) s_cnt = 0;

    float4 e[8];
    #pragma unroll
    for (int j = 0; j < 8; ++j) e[j] = part[(size_t)row * 8 + j];
    Top2 t{-3.4e38f, 0x7fffffff, -3.4e38f, 0x7fffffff};
    #pragma unroll
    for (int j = 0; j < 8; ++j) {
        Top2 o{e[j].x, __float_as_int(e[j].y), e[j].z, __float_as_int(e[j].w)};
        t = merge2(t, o);
    }
    int best = t.i1;
    const float MARGIN = 0.12f;   // ~7.7 sigma of f16-screen score-diff noise
    const float cut = t.s1 - MARGIN;
    const bool need = (t.s1 - t.s2 < MARGIN);
    __syncthreads();              // s_cnt initialized

    int nc = 0;
    if (need) {
        #pragma unroll
        for (int j = 0; j < 8; ++j)
            #pragma unroll
            for (int c = 0; c < 2; ++c) {
                float sv = c ? e[j].z : e[j].x;
                int   ci = __float_as_int(c ? e[j].w : e[j].y);
                nc += (sv >= cut && (unsigned)ci < 8192u) ? 1 : 0;
            }
    }
    int mybase = 0;
    bool serial = false;
    if (nc) {
        mybase = atomicAdd(&s_cnt, nc);
        if (mybase + nc <= 2048) {
            int k = 0;
            #pragma unroll
            for (int j = 0; j < 8; ++j)
                #pragma unroll
                for (int c = 0; c < 2; ++c) {
                    float sv = c ? e[j].z : e[j].x;
                    int   ci = __float_as_int(c ? e[j].w : e[j].y);
                    if (sv >= cut && (unsigned)ci < 8192u)
                        ent[mybase + (k++)] = make_int2(row, ci);
                }
        } else serial = true;     // overflow fallback (needs >8 cands/row avg)
    }
    __syncthreads();
    const int cnt = (s_cnt < 2048) ? s_cnt : 2048;
    const int wave = tid >> 6, lane = tid & 63;
    for (int ee = wave; ee < cnt; ee += 4) {
        int2 rc = ent[ee];
        float4 c4 = ((const float4*)(cb + (size_t)rc.y * 256))[lane];
        float4 z4 = (lane < 32)
                  ? ((const float4*)(gr + (size_t)rc.x * 128))[lane]
                  : ((const float4*)(gi + (size_t)rc.x * 128))[lane - 32];
        double dx = (double)z4.x - (double)c4.x;
        double dy = (double)z4.y - (double)c4.y;
        double dz = (double)z4.z - (double)c4.z;
        double dw = (double)z4.w - (double)c4.w;
        double d = dx * dx + dy * dy + dz * dz + dw * dw;
        #pragma unroll
        for (int m = 1; m < 64; m <<= 1) d += __shfl_xor(d, m);
        if (lane == 0) res[ee] = d;
    }
    __syncthreads();
    if (nc && !serial) {
        double bd = 1e300; int bi = 0x7fffffff;
        for (int k = 0; k < nc; ++k) {
            double d = res[mybase + k];
            int   ci = ent[mybase + k].y;
            if (d < bd || (d == bd && ci < bi)) { bd = d; bi = ci; }
        }
        if ((unsigned)bi < 8192u) best = bi;
    } else if (serial) {          // old proven serial path (rare)
        double bd = 1e300; int bi = 0x7fffffff;
        const float* zr = gr + (size_t)row * 128;
        const float* zi = gi + (size_t)row * 128;
        #pragma unroll
        for (int j = 0; j < 8; ++j)
            #pragma unroll
            for (int c = 0; c < 2; ++c) {
                float sv = c ? e[j].z : e[j].x;
                int   ci = __float_as_int(c ? e[j].w : e[j].y);
                if (sv >= cut && (unsigned)ci < 8192u) {
                    const float* crow = cb + (size_t)ci * 256;
                    double d = 0.0;
                    for (int k = 0; k < 128; ++k) {
                        double a = (double)zr[k] - (double)crow[k];
                        double b = (double)zi[k] - (double)crow[128 + k];
                        d += a * a + b * b;
                    }
                    if (d < bd || (d == bd && ci < bi)) { bd = d; bi = ci; }
                }
            }
        if ((unsigned)bi < 8192u) best = bi;
    }
    idx[row] = ((unsigned)best < 8192u) ? best : 0;
}

// ---- 5. gather + proposal(REAL part only) + salience + vq (one wave/row) ----
__global__ __launch_bounds__(256) void gather_epi(const int* __restrict__ idx,
                                                  const float* __restrict__ gr,
                                                  const float* __restrict__ gi,
                                                  const float* __restrict__ cb,
                                                  const float* __restrict__ salw,
                                                  const float* __restrict__ salb,
                                                  float* __restrict__ out,
                                                  size_t sal_off, size_t vq_off) {
    const int wave = threadIdx.x >> 6, lane = threadIdx.x & 63;
    const int row = blockIdx.x * 4 + wave;
    int id = idx[row];
    if ((unsigned)id >= 8192u) id = 0;   // clamp: no wild reads

    float4 c4 = ((const float4*)(cb + (size_t)id * 256))[lane];
    float4 z4 = (lane < 32) ? ((const float4*)(gr + (size_t)row * 128))[lane]
                            : ((const float4*)(gi + (size_t)row * 128))[lane - 32];

    float dx = c4.x - z4.x, dy = c4.y - z4.y, dz = c4.z - z4.z, dw = c4.w - z4.w;
    float vq = dx * dx + dy * dy + dz * dz + dw * dw;
    float4 w4 = ((const float4*)salw)[lane];
    float sal = c4.x * w4.x + c4.y * w4.y + c4.z * w4.z + c4.w * w4.w;
    #pragma unroll
    for (int m = 1; m < 64; m <<= 1) {
        vq  += __shfl_xor(vq, m);
        sal += __shfl_xor(sal, m);
    }

    // proposal: real part only — lanes 0..31 hold c[0..128) as float4s
    if (lane < 32 && (size_t)(row + 1) * 128 <= sal_off) {
        float4* op = (float4*)(out + (size_t)row * 128);
        op[lane] = c4;
    }
    if (lane == 0 && sal_off + row < vq_off)
        out[sal_off + row] = sal + salb[0];

    __shared__ float vqs[4];
    if (lane == 0) vqs[wave] = vq;
    __syncthreads();
    if (threadIdx.x == 0) {
        float p = (vqs[0] + vqs[1] + vqs[2] + vqs[3]) * (1.25f / 8388608.f);
        atomicAdd(out + vq_off, p);
    }
}

extern "C" void kernel_launch(void* const* d_in, const int* in_sizes, int n_in,
                              void* d_out, int out_size, void* d_ws, size_t ws_size,
                              hipStream_t stream) {
    const float* gr = (const float*)d_in[0];   // gw_real  [8,4096,128]
    const float* gi = (const float*)d_in[1];   // gw_imag  [8,4096,128]
    const float* cb = (const float*)d_in[2];   // codebook [8192,256]
    const float* sw = (const float*)d_in[3];   // sal_w    [1,256]
    const float* sb = (const float*)d_in[4];   // sal_b    [1]
    float* out = (float*)d_out;

    // Output offsets (out_size = 4,227,073 floats:
    // proposal-real 4,194,304 | salience 32,768 | vq_loss 1).
    size_t vq_off  = (size_t)out_size - 1;
    size_t sal_off = (size_t)out_size - 1 - 32768;

    char* base = (char*)d_ws;
    int*  idxb = (int*)(base + IDX_OFF);
    _Float16* A    = (_Float16*)(base + A_OFF);
    _Float16* Bq   = (_Float16*)(base + B_OFF);
    float*    cn   = (float*)   (base + CN_OFF);
    float4*   part = (float4*)  (base + PART_OFF);

    prep_z<<<8192, 256, 0, stream>>>(gr, gi, A);
    prep_c<<<8192, 64, 0, stream>>>(cb, Bq, cn);
    gemm_argmin<<<512, 256, 0, stream>>>(A, Bq, cn, part);
    resolve<<<128, 256, 0, stream>>>(part, gr, gi, cb, idxb, out, vq_off);
    gather_epi<<<8192, 256, 0, stream>>>(idxb, gr, gi, cb, sw, sb, out,
                                         sal_off, vq_off);
}